// Round 14
// baseline (120.755 us; speedup 1.0000x reference)
//
#include <hip/hip_runtime.h>
#include <hip/hip_cooperative_groups.h>
#include <hip/hip_bf16.h>
#include <cstddef>
#include <cstdint>

namespace cg = cooperative_groups;

#define BB    8
#define TT    2048
#define KIN   1024
#define NOUT  512
#define CHUNK 32
#define NCHUNK (TT / CHUNK)   // 64

#define BM 128
#define BN 128
#define BK 64
#define NKSTEP (KIN / BK)     // 16
#define NPAGE  (KIN / 32)     // 32 8KB pages per 128-row strip (W only)
#define TILEB 8192

typedef __attribute__((ext_vector_type(4))) float          f32x4;
typedef __attribute__((ext_vector_type(4))) unsigned int   u32x4;
typedef _Float16 f16x8 __attribute__((ext_vector_type(8)));

// ---------------------------------------------------------------------------
// W f32 -> f16 tiled+preswizzled pages (verified R10-R13).
// ---------------------------------------------------------------------------
__global__ __launch_bounds__(256) void conv_tiled_f16(
    const float* __restrict__ src, unsigned char* __restrict__ dst, int total) {
  int idx = blockIdx.x * blockDim.x + threadIdx.x;
  const int stride = gridDim.x * blockDim.x;
  for (; idx < total; idx += stride) {
    const int r  = idx >> 7;
    const int s8 = idx & 127;
    const float* p = src + (size_t)r * KIN + s8 * 8;
    float4 a = *reinterpret_cast<const float4*>(p);
    float4 b = *reinterpret_cast<const float4*>(p + 4);
    f16x8 h;
    h[0] = (_Float16)a.x; h[1] = (_Float16)a.y;
    h[2] = (_Float16)a.z; h[3] = (_Float16)a.w;
    h[4] = (_Float16)b.x; h[5] = (_Float16)b.y;
    h[6] = (_Float16)b.z; h[7] = (_Float16)b.w;
    const int row  = r & 127;
    const int page = (r >> 7) * NPAGE + (s8 >> 2);
    const int slot = (s8 & 3) ^ ((row >> 1) & 3);
    *reinterpret_cast<f16x8*>(dst + (size_t)page * TILEB + row * 64 + slot * 16) = h;
  }
}

#define G2L(gp, sp)                                                        \
  __builtin_amdgcn_global_load_lds(                                       \
      (const __attribute__((address_space(1))) void*)(gp),                \
      (__attribute__((address_space(3))) void*)(sp), 16, 0, 0)

// ---------------------------------------------------------------------------
// COOPERATIVE fused GEMM + scan.  Phase 1 = R12's verified gemm core
// (direct f32 X via pre-swizzled G2L, 128x128, BK=64, 2-barrier drain) with
// bias added into acc + vend epilogue.  grid.sync().  Phase 2 = per-wave LDS
// stash of the 64x64 f32 quadrant, per-column carry compose from vend, 64-row
// sequential scan in-register, coalesced stores of out + states.
// grid (128,4) = 512 blocks = exactly 2/CU at 64KB LDS (co-resident).
// ---------------------------------------------------------------------------
__global__ __launch_bounds__(256, 2) void fused_gemm_scan(
    const float* __restrict__ X, const unsigned char* __restrict__ Wt,
    const float* __restrict__ bias, const float* __restrict__ decay,
    float* __restrict__ out, float* __restrict__ states,
    float* __restrict__ vend) {
  __shared__ __align__(16) unsigned char smem[65536];  // gemm: A 32K | B 16K

  const int tid  = threadIdx.x;
  const int wave = tid >> 6;
  const int lane = tid & 63;
  const int m0 = blockIdx.x * BM;
  const int n0 = blockIdx.y * BN;
  const int wm = (wave >> 1) * 64;
  const int wn = (wave & 1) * 64;
  const int frow = lane & 15;
  const int g    = lane >> 4;

  unsigned char* sA = smem;
  unsigned char* sB = smem + 32768;

  // --- A staging (verified R12): per-lane inverse-swizzled f32 source ---
  const int arow4 = wave * 4 + (lane >> 4);
  const int aslot = lane & 15;
  const float* gA = X + (size_t)(m0 + arow4) * KIN + ((aslot ^ (arow4 & 7)) << 2);
  const int ldsw = wave * 1024;

  const unsigned char* srcB = Wt + (size_t)(n0 >> 7) * NPAGE * TILEB + tid * 16;

  const int arswz = frow & 7;
  const int swzr  = (g ^ ((frow >> 1) & 3)) << 4;

  f32x4 acc[4][4] = {};

  for (int t = 0; t < NKSTEP; ++t) {
    __syncthreads();
    const int k0 = t * BK;
#pragma unroll
    for (int q = 0; q < 8; ++q)
      G2L(gA + (size_t)(q * 16) * KIN + k0, sA + q * 4096 + ldsw);
    const size_t boff = (size_t)(2 * t) * TILEB;
#pragma unroll
    for (int q = 0; q < 4; ++q)
      G2L(srcB + boff + q * 4096, sB + q * 4096 + ldsw);
    __syncthreads();

#pragma unroll
    for (int kk = 0; kk < 2; ++kk) {
      f16x8 af[4];
#pragma unroll
      for (int mi = 0; mi < 4; ++mi) {
        const int row = wm + mi * 16 + frow;
        const unsigned char* ap = sA + row * 256;
        const int ks0 = kk * 8 + g * 2;
        f32x4 q0 = *reinterpret_cast<const f32x4*>(ap + ((ks0    ) ^ arswz) * 16);
        f32x4 q1 = *reinterpret_cast<const f32x4*>(ap + ((ks0 + 1) ^ arswz) * 16);
        u32x4 hv;
        hv[0] = __builtin_bit_cast(unsigned int, __builtin_amdgcn_cvt_pkrtz(q0[0], q0[1]));
        hv[1] = __builtin_bit_cast(unsigned int, __builtin_amdgcn_cvt_pkrtz(q0[2], q0[3]));
        hv[2] = __builtin_bit_cast(unsigned int, __builtin_amdgcn_cvt_pkrtz(q1[0], q1[1]));
        hv[3] = __builtin_bit_cast(unsigned int, __builtin_amdgcn_cvt_pkrtz(q1[2], q1[3]));
        af[mi] = __builtin_bit_cast(f16x8, hv);
      }
#pragma unroll
      for (int ni = 0; ni < 4; ++ni) {
        f16x8 bf = *reinterpret_cast<const f16x8*>(
            sB + kk * 8192 + (wn + ni * 16 + frow) * 64 + swzr);
#pragma unroll
        for (int mi = 0; mi < 4; ++mi)
          acc[mi][ni] = __builtin_amdgcn_mfma_f32_16x16x32_f16(af[mi], bf, acc[mi][ni], 0, 0, 0);
      }
    }
  }

  // --- bias into acc (so vend + phase 2 use final `current`) ---
  const int colb = n0 + wn + frow;
#pragma unroll
  for (int ni = 0; ni < 4; ++ni) {
    const float bv = bias[colb + ni * 16];
#pragma unroll
    for (int mi = 0; mi < 4; ++mi)
#pragma unroll
      for (int r = 0; r < 4; ++r) acc[mi][ni][r] += bv;
  }

  // --- vend epilogue (verified R11/R12; bias pre-added) ---
  {
    float rlo[4], rhi[4];
#pragma unroll
    for (int ni = 0; ni < 4; ++ni) {
      const float d  = decay[colb + ni * 16];
      const float omd = 1.0f - d;
      const float dd = d * d, d4 = dd * dd, d8 = d4 * d4;
      const float d16 = d8 * d8, d12 = d8 * d4;
      const float dpg = (g == 0) ? d12 : (g == 1) ? d8 : (g == 2) ? d4 : 1.0f;
      float s[4];
#pragma unroll
      for (int mi = 0; mi < 4; ++mi) {
        float v = acc[mi][ni][0];
        v = v * d + acc[mi][ni][1];
        v = v * d + acc[mi][ni][2];
        v = v * d + acc[mi][ni][3];
        s[mi] = omd * v;
      }
      float ulo = dpg * (s[0] * d16 + s[1]);
      float uhi = dpg * (s[2] * d16 + s[3]);
      ulo += __shfl_xor(ulo, 16); ulo += __shfl_xor(ulo, 32);
      uhi += __shfl_xor(uhi, 16); uhi += __shfl_xor(uhi, 32);
      rlo[ni] = ulo; rhi[ni] = uhi;
    }
    const int b   = m0 >> 11;
    const int clo = ((m0 & (TT - 1)) >> 5) + (wm >> 5);
    const int chunk = clo + (g >> 1);
    const int half  = g >> 1;
    const int nia   = g & 1;
    const float v1 = half ? (nia ? rhi[1] : rhi[0]) : (nia ? rlo[1] : rlo[0]);
    const float v2 = half ? (nia ? rhi[3] : rhi[2]) : (nia ? rlo[3] : rlo[2]);
    const int col1 = n0 + wn + frow + nia * 16;
    float* vp = vend + ((size_t)b * NCHUNK + chunk) * NOUT;
    vp[col1]      = v1;
    vp[col1 + 32] = v2;
  }

  // ======================= grid-wide sync =======================
  cg::this_grid().sync();

  // --- phase 2: stash quadrant, compose carry, scan, store ---
  float* smf = reinterpret_cast<float*>(smem) + wave * 4096;  // 64x64 f32
#pragma unroll
  for (int mi = 0; mi < 4; ++mi)
#pragma unroll
    for (int r = 0; r < 4; ++r)
#pragma unroll
      for (int ni = 0; ni < 4; ++ni)
        smf[(mi * 16 + g * 4 + r) * 64 + ni * 16 + frow] = acc[mi][ni][r];
  __syncthreads();

  {
    const int col = n0 + wn + lane;
    const float d   = decay[col];
    const float omd = 1.0f - d;
    const float dd = d * d, d4 = dd * dd, d8 = d4 * d4, d16 = d8 * d8;
    const float dL = d16 * d16;   // d^32
    const int b      = m0 >> 11;
    const int trow   = (m0 & (TT - 1)) + wm;       // first t of this quadrant
    const int chunk0 = trow >> 5;

    float v = 0.0f;
    const float* vp = vend + (size_t)b * NCHUNK * NOUT + col;
    for (int cc = 0; cc < chunk0; ++cc) v = dL * v + vp[(size_t)cc * NOUT];

    size_t oidx = ((size_t)b * TT + trow) * NOUT + col;
    size_t sidx = ((size_t)b * (TT + 1) + trow + 1) * NOUT + col;
    for (int j = 0; j < 64; ++j) {
      v = d * v + omd * smf[j * 64 + lane];
      out[oidx]    = v;
      states[sidx] = v;
      oidx += NOUT; sidx += NOUT;
    }
    if (trow == 0) states[((size_t)b * (TT + 1)) * NOUT + col] = 0.0f;
  }
}

// ---------------------------------------------------------------------------
// Fallback path (R12, fully verified): gemm -> Cws + vend, then fixup.
// ---------------------------------------------------------------------------
__global__ __launch_bounds__(256, 2) void gemm_f16(
    const float* __restrict__ X, const unsigned char* __restrict__ Wt,
    const float* __restrict__ bias, const float* __restrict__ decay,
    unsigned short* __restrict__ Cws, float* __restrict__ vend) {
  __shared__ __align__(16) unsigned char smem[32768 + 16384];
  const int tid  = threadIdx.x;
  const int wave = tid >> 6;
  const int lane = tid & 63;
  const int m0 = blockIdx.x * BM;
  const int n0 = blockIdx.y * BN;
  const int wm = (wave >> 1) * 64;
  const int wn = (wave & 1) * 64;
  const int frow = lane & 15;
  const int g    = lane >> 4;
  unsigned char* sA = smem;
  unsigned char* sB = smem + 32768;
  const int arow4 = wave * 4 + (lane >> 4);
  const int aslot = lane & 15;
  const float* gA = X + (size_t)(m0 + arow4) * KIN + ((aslot ^ (arow4 & 7)) << 2);
  const int ldsw = wave * 1024;
  const unsigned char* srcB = Wt + (size_t)(n0 >> 7) * NPAGE * TILEB + tid * 16;
  const int arswz = frow & 7;
  const int swzr  = (g ^ ((frow >> 1) & 3)) << 4;
  f32x4 acc[4][4] = {};
  for (int t = 0; t < NKSTEP; ++t) {
    __syncthreads();
    const int k0 = t * BK;
#pragma unroll
    for (int q = 0; q < 8; ++q)
      G2L(gA + (size_t)(q * 16) * KIN + k0, sA + q * 4096 + ldsw);
    const size_t boff = (size_t)(2 * t) * TILEB;
#pragma unroll
    for (int q = 0; q < 4; ++q)
      G2L(srcB + boff + q * 4096, sB + q * 4096 + ldsw);
    __syncthreads();
#pragma unroll
    for (int kk = 0; kk < 2; ++kk) {
      f16x8 af[4];
#pragma unroll
      for (int mi = 0; mi < 4; ++mi) {
        const int row = wm + mi * 16 + frow;
        const unsigned char* ap = sA + row * 256;
        const int ks0 = kk * 8 + g * 2;
        f32x4 q0 = *reinterpret_cast<const f32x4*>(ap + ((ks0    ) ^ arswz) * 16);
        f32x4 q1 = *reinterpret_cast<const f32x4*>(ap + ((ks0 + 1) ^ arswz) * 16);
        u32x4 hv;
        hv[0] = __builtin_bit_cast(unsigned int, __builtin_amdgcn_cvt_pkrtz(q0[0], q0[1]));
        hv[1] = __builtin_bit_cast(unsigned int, __builtin_amdgcn_cvt_pkrtz(q0[2], q0[3]));
        hv[2] = __builtin_bit_cast(unsigned int, __builtin_amdgcn_cvt_pkrtz(q1[0], q1[1]));
        hv[3] = __builtin_bit_cast(unsigned int, __builtin_amdgcn_cvt_pkrtz(q1[2], q1[3]));
        af[mi] = __builtin_bit_cast(f16x8, hv);
      }
#pragma unroll
      for (int ni = 0; ni < 4; ++ni) {
        f16x8 bf = *reinterpret_cast<const f16x8*>(
            sB + kk * 8192 + (wn + ni * 16 + frow) * 64 + swzr);
#pragma unroll
        for (int mi = 0; mi < 4; ++mi)
          acc[mi][ni] = __builtin_amdgcn_mfma_f32_16x16x32_f16(af[mi], bf, acc[mi][ni], 0, 0, 0);
      }
    }
  }
  const int colb = n0 + wn + frow;
  const int rowb = m0 + wm + (g << 2);
  float bv[4];
#pragma unroll
  for (int ni = 0; ni < 4; ++ni) bv[ni] = bias[colb + ni * 16];
#pragma unroll
  for (int mi = 0; mi < 4; ++mi)
#pragma unroll
    for (int r = 0; r < 4; ++r)
#pragma unroll
      for (int ni = 0; ni < 4; ++ni) {
        const _Float16 hv = (_Float16)(acc[mi][ni][r] + bv[ni]);
        Cws[(size_t)(rowb + mi * 16 + r) * NOUT + colb + ni * 16] =
            __builtin_bit_cast(unsigned short, hv);
      }
  {
    float rlo[4], rhi[4];
#pragma unroll
    for (int ni = 0; ni < 4; ++ni) {
      const float d  = decay[colb + ni * 16];
      const float bb = bv[ni];
      const float omd = 1.0f - d;
      const float dd = d * d, d4 = dd * dd, d8 = d4 * d4;
      const float d16 = d8 * d8, d12 = d8 * d4;
      const float dpg = (g == 0) ? d12 : (g == 1) ? d8 : (g == 2) ? d4 : 1.0f;
      float s[4];
#pragma unroll
      for (int mi = 0; mi < 4; ++mi) {
        float v = acc[mi][ni][0] + bb;
        v = v * d + (acc[mi][ni][1] + bb);
        v = v * d + (acc[mi][ni][2] + bb);
        v = v * d + (acc[mi][ni][3] + bb);
        s[mi] = omd * v;
      }
      float ulo = dpg * (s[0] * d16 + s[1]);
      float uhi = dpg * (s[2] * d16 + s[3]);
      ulo += __shfl_xor(ulo, 16); ulo += __shfl_xor(ulo, 32);
      uhi += __shfl_xor(uhi, 16); uhi += __shfl_xor(uhi, 32);
      rlo[ni] = ulo; rhi[ni] = uhi;
    }
    const int b   = m0 >> 11;
    const int clo = ((m0 & (TT - 1)) >> 5) + (wm >> 5);
    const int chunk = clo + (g >> 1);
    const int half  = g >> 1;
    const int nia   = g & 1;
    const float v1 = half ? (nia ? rhi[1] : rhi[0]) : (nia ? rlo[1] : rlo[0]);
    const float v2 = half ? (nia ? rhi[3] : rhi[2]) : (nia ? rlo[3] : rlo[2]);
    const int col1 = n0 + wn + frow + nia * 16;
    float* vp = vend + ((size_t)b * NCHUNK + chunk) * NOUT;
    vp[col1]      = v1;
    vp[col1 + 32] = v2;
  }
}

__global__ __launch_bounds__(512) void scan_fixup2(
    const unsigned short* __restrict__ Cws, const float* __restrict__ vend,
    const float* __restrict__ decay, float* __restrict__ out,
    float* __restrict__ states) {
  const int b = blockIdx.x / NCHUNK;
  const int c = blockIdx.x % NCHUNK;
  const int o = threadIdx.x;
  const float d   = decay[o];
  const float omd = 1.0f - d;
  const float dd = d * d, d4 = dd * dd, d8 = d4 * d4, d16 = d8 * d8;
  const float dL = d16 * d16;
  float v = 0.0f;
  const float* vp = vend + (size_t)b * NCHUNK * NOUT + o;
  for (int cc = 0; cc < c; ++cc) v = dL * v + vp[(size_t)cc * NOUT];
  size_t obase = ((size_t)b * TT + (size_t)c * CHUNK) * NOUT + o;
  size_t sbase = ((size_t)b * (TT + 1) + (size_t)c * CHUNK + 1) * NOUT + o;
#pragma unroll 4
  for (int k = 0; k < CHUNK; ++k) {
    const unsigned short hu = Cws[obase + (size_t)k * NOUT];
    const float cur = (float)__builtin_bit_cast(_Float16, hu);
    v = d * v + omd * cur;
    out[obase + (size_t)k * NOUT]    = v;
    states[sbase + (size_t)k * NOUT] = v;
  }
  if (c == 0) states[((size_t)b * (TT + 1)) * NOUT + o] = 0.0f;
}

__global__ __launch_bounds__(256) void gemm_f32_64x64(
    const float* __restrict__ X, const float* __restrict__ W,
    const float* __restrict__ bias, float* __restrict__ C) {
  __shared__ float As[16][65];
  __shared__ float Bs[16][65];
  const int m0  = blockIdx.y * 64;
  const int n0  = blockIdx.x * 64;
  const int tid = threadIdx.x;
  const int tx  = tid & 15;
  const int ty  = tid >> 4;
  const int lr  = tid >> 2;
  const int lk  = (tid & 3) << 2;
  float acc[4][4] = {};
  const float* xa = X + (size_t)(m0 + lr) * KIN + lk;
  const float* wb = W + (size_t)(n0 + lr) * KIN + lk;
  for (int k0 = 0; k0 < KIN; k0 += 16) {
    float4 av = *reinterpret_cast<const float4*>(xa + k0);
    float4 bv = *reinterpret_cast<const float4*>(wb + k0);
    As[lk + 0][lr] = av.x; As[lk + 1][lr] = av.y;
    As[lk + 2][lr] = av.z; As[lk + 3][lr] = av.w;
    Bs[lk + 0][lr] = bv.x; Bs[lk + 1][lr] = bv.y;
    Bs[lk + 2][lr] = bv.z; Bs[lk + 3][lr] = bv.w;
    __syncthreads();
#pragma unroll
    for (int k = 0; k < 16; ++k) {
      float a[4], b[4];
#pragma unroll
      for (int i = 0; i < 4; ++i) a[i] = As[k][ty * 4 + i];
#pragma unroll
      for (int j = 0; j < 4; ++j) b[j] = Bs[k][tx * 4 + j];
#pragma unroll
      for (int i = 0; i < 4; ++i)
#pragma unroll
        for (int j = 0; j < 4; ++j) acc[i][j] += a[i] * b[j];
    }
    __syncthreads();
  }
  const int n = n0 + tx * 4;
  float4 bv = *reinterpret_cast<const float4*>(&bias[n]);
#pragma unroll
  for (int i = 0; i < 4; ++i) {
    const int m = m0 + ty * 4 + i;
    float4 r;
    r.x = acc[i][0] + bv.x; r.y = acc[i][1] + bv.y;
    r.z = acc[i][2] + bv.z; r.w = acc[i][3] + bv.w;
    *reinterpret_cast<float4*>(&C[(size_t)m * NOUT + n]) = r;
  }
}

__global__ __launch_bounds__(512) void scan_seq(
    float* __restrict__ C, float* __restrict__ states,
    const float* __restrict__ decay) {
  const int b = blockIdx.x;
  const int o = threadIdx.x;
  const float d   = decay[o];
  const float omd = 1.0f - d;
  float v = 0.0f;
  states[((size_t)b * (TT + 1)) * NOUT + o] = 0.0f;
  for (int t = 0; t < TT; ++t) {
    const size_t oi = ((size_t)b * TT + t) * NOUT + o;
    float x = C[oi];
    v = d * v + omd * x;
    C[oi] = v;
    states[((size_t)b * (TT + 1) + t + 1) * NOUT + o] = v;
  }
}

extern "C" void kernel_launch(void* const* d_in, const int* in_sizes, int n_in,
                              void* d_out, int out_size, void* d_ws, size_t ws_size,
                              hipStream_t stream) {
  const float* x     = (const float*)d_in[0];
  const float* w     = (const float*)d_in[1];
  const float* bias  = (const float*)d_in[2];
  const float* decay = (const float*)d_in[3];

  float* out    = (float*)d_out;
  float* states = out + (size_t)BB * TT * NOUT;

  const size_t szWb = (size_t)NOUT * KIN * sizeof(_Float16);        // 1 MB
  const size_t scan_elems = (size_t)BB * NCHUNK * NOUT;
  const size_t szVd = scan_elems * sizeof(float);                   // 1 MB
  const size_t szCb = (size_t)BB * TT * NOUT * sizeof(_Float16);    // 16.8 MB (fallback)
  const size_t need = szWb + szVd + szCb;

  if (ws_size >= need) {
    unsigned char*  Wt   = (unsigned char*)d_ws;
    float*          vend = (float*)(Wt + szWb);
    unsigned short* Cws  = (unsigned short*)((unsigned char*)d_ws + szWb + szVd);

    conv_tiled_f16<<<256, 256, 0, stream>>>(w, Wt, NOUT * (KIN / 8));

    void* args[] = {(void*)&x, (void*)&Wt, (void*)&bias, (void*)&decay,
                    (void*)&out, (void*)&states, (void*)&vend};
    hipError_t err = hipLaunchCooperativeKernel(
        reinterpret_cast<void*>(fused_gemm_scan),
        dim3((BB * TT) / BM, NOUT / BN), dim3(256), args, 0, stream);
    if (err != hipSuccess) {
      // fallback: verified R12 3-kernel path
      gemm_f16<<<dim3((BB * TT) / BM, NOUT / BN), 256, 0, stream>>>(
          x, Wt, bias, decay, Cws, vend);
      scan_fixup2<<<BB * NCHUNK, NOUT, 0, stream>>>(Cws, vend, decay, out, states);
    }
  } else {
    gemm_f32_64x64<<<dim3(NOUT / 64, (BB * TT) / 64), 256, 0, stream>>>(x, w, bias, out);
    scan_seq<<<BB, NOUT, 0, stream>>>(out, states, decay);
  }
}

// Round 15
// 66.805 us; speedup vs baseline: 1.8076x; 1.8076x over previous
//
#include <hip/hip_runtime.h>
#include <hip/hip_bf16.h>
#include <cstddef>
#include <cstdint>

#define BB    8
#define TT    2048
#define KIN   1024
#define NOUT  512
#define CHUNK 32
#define NCHUNK (TT / CHUNK)   // 64

#define BM 64
#define BN 128
#define BK 64
#define NKSTEP (KIN / BK)     // 16
#define NPAGE  (KIN / 32)     // 32 8KB pages per 128-row strip (W only)
#define TILEB 8192

typedef __attribute__((ext_vector_type(4))) float          f32x4;
typedef __attribute__((ext_vector_type(4))) unsigned int   u32x4;
typedef _Float16 f16x8 __attribute__((ext_vector_type(8)));

// ---------------------------------------------------------------------------
// W f32 -> f16 tiled+preswizzled pages (verified R10-R14).  1 MB, ~3 us.
// ---------------------------------------------------------------------------
__global__ __launch_bounds__(256) void conv_tiled_f16(
    const float* __restrict__ src, unsigned char* __restrict__ dst, int total) {
  int idx = blockIdx.x * blockDim.x + threadIdx.x;
  const int stride = gridDim.x * blockDim.x;
  for (; idx < total; idx += stride) {
    const int r  = idx >> 7;
    const int s8 = idx & 127;
    const float* p = src + (size_t)r * KIN + s8 * 8;
    float4 a = *reinterpret_cast<const float4*>(p);
    float4 b = *reinterpret_cast<const float4*>(p + 4);
    f16x8 h;
    h[0] = (_Float16)a.x; h[1] = (_Float16)a.y;
    h[2] = (_Float16)a.z; h[3] = (_Float16)a.w;
    h[4] = (_Float16)b.x; h[5] = (_Float16)b.y;
    h[6] = (_Float16)b.z; h[7] = (_Float16)b.w;
    const int row  = r & 127;
    const int page = (r >> 7) * NPAGE + (s8 >> 2);
    const int slot = (s8 & 3) ^ ((row >> 1) & 3);
    *reinterpret_cast<f16x8*>(dst + (size_t)page * TILEB + row * 64 + slot * 16) = h;
  }
}

#define G2L(gp, sp)                                                        \
  __builtin_amdgcn_global_load_lds(                                       \
      (const __attribute__((address_space(1))) void*)(gp),                \
      (__attribute__((address_space(3))) void*)(sp), 16, 0, 0)

// ---------------------------------------------------------------------------
// fp16 MFMA GEMM — R12's verified core at 4-blocks/CU occupancy:
//   64x128 tile, BK=64, 4 waves (32x64 each), 32KB LDS (A f32 16KB | B 16KB),
//   direct f32 X via inverse-swizzled G2L (rule #21; R12-verified), f16 W
//   pages linear G2L (R10-verified), 2-barrier drain loop, cvt_pkrtz at
//   fragment-read, 16 MFMA/wave-step.
//   grid (256 m, 4 n) = 1024 blocks = 4 RESIDENT/CU (m114: co-resident
//   blocks hide each other's vmcnt drains — R13 measured ~25% core gain).
//   C stored f16 to ws; fused vend = R13's 1-chunk-per-wave epilogue.
//   256 % 8 == 0 -> an m-strip's 4 n-blocks share an XCD (verified R3+).
// ---------------------------------------------------------------------------
__global__ __launch_bounds__(256, 4) void gemm_f16(
    const float* __restrict__ X, const unsigned char* __restrict__ Wt,
    const float* __restrict__ bias, const float* __restrict__ decay,
    unsigned short* __restrict__ Cws, float* __restrict__ vend) {
  __shared__ __align__(16) unsigned char smem[16384 + 16384];  // A f32 | B f16

  const int tid  = threadIdx.x;
  const int wave = tid >> 6;
  const int lane = tid & 63;
  const int m0 = blockIdx.x * BM;
  const int n0 = blockIdx.y * BN;
  const int wm = (wave >> 1) * 32;   // 2x2 waves: 32x64 output each
  const int wn = (wave & 1) * 64;
  const int frow = lane & 15;
  const int g    = lane >> 4;

  unsigned char* sA = smem;
  unsigned char* sB = smem + 16384;

  // --- A staging (R12-verified map, 4 issues of 16 rows): LDS[row][slot] =
  //     X[row][slot^(row&7)] with 16B f32 slots; row = q*16 + arow4. ---
  const int arow4 = wave * 4 + (lane >> 4);
  const int aslot = lane & 15;
  const float* gA = X + (size_t)(m0 + arow4) * KIN + ((aslot ^ (arow4 & 7)) << 2);
  const int ldsw = wave * 1024;

  const unsigned char* srcB = Wt + (size_t)(n0 >> 7) * NPAGE * TILEB + tid * 16;

  const int arswz = frow & 7;
  const int swzr  = (g ^ ((frow >> 1) & 3)) << 4;

  f32x4 acc[2][4] = {};

  for (int t = 0; t < NKSTEP; ++t) {
    __syncthreads();                       // prev compute done
    const int k0 = t * BK;
#pragma unroll
    for (int q = 0; q < 4; ++q)            // A: 4 issues x 16 rows x 256B
      G2L(gA + (size_t)(q * 16) * KIN + k0, sA + q * 4096 + ldsw);
    const size_t boff = (size_t)(2 * t) * TILEB;
#pragma unroll
    for (int q = 0; q < 4; ++q)            // B: two contiguous 8KB pages
      G2L(srcB + boff + q * 4096, sB + q * 4096 + ldsw);
    __syncthreads();                       // vmcnt drained -> tiles ready

#pragma unroll
    for (int kk = 0; kk < 2; ++kk) {
      f16x8 af[2];
#pragma unroll
      for (int mi = 0; mi < 2; ++mi) {
        const int row = wm + mi * 16 + frow;
        const unsigned char* ap = sA + row * 256;
        const int ks0 = kk * 8 + g * 2;
        f32x4 q0 = *reinterpret_cast<const f32x4*>(ap + ((ks0    ) ^ arswz) * 16);
        f32x4 q1 = *reinterpret_cast<const f32x4*>(ap + ((ks0 + 1) ^ arswz) * 16);
        u32x4 hv;
        hv[0] = __builtin_bit_cast(unsigned int, __builtin_amdgcn_cvt_pkrtz(q0[0], q0[1]));
        hv[1] = __builtin_bit_cast(unsigned int, __builtin_amdgcn_cvt_pkrtz(q0[2], q0[3]));
        hv[2] = __builtin_bit_cast(unsigned int, __builtin_amdgcn_cvt_pkrtz(q1[0], q1[1]));
        hv[3] = __builtin_bit_cast(unsigned int, __builtin_amdgcn_cvt_pkrtz(q1[2], q1[3]));
        af[mi] = __builtin_bit_cast(f16x8, hv);
      }
#pragma unroll
      for (int ni = 0; ni < 4; ++ni) {
        f16x8 bf = *reinterpret_cast<const f16x8*>(
            sB + kk * 8192 + (wn + ni * 16 + frow) * 64 + swzr);
#pragma unroll
        for (int mi = 0; mi < 2; ++mi)
          acc[mi][ni] = __builtin_amdgcn_mfma_f32_16x16x32_f16(af[mi], bf, acc[mi][ni], 0, 0, 0);
      }
    }
  }

  // --- epilogue: bias + f16 C store to workspace (verified R11/R12) ---
  const int colb = n0 + wn + frow;
  const int rowb = m0 + wm + (g << 2);
  float bv[4];
#pragma unroll
  for (int ni = 0; ni < 4; ++ni) bv[ni] = bias[colb + ni * 16];
#pragma unroll
  for (int mi = 0; mi < 2; ++mi) {
#pragma unroll
    for (int r = 0; r < 4; ++r) {
#pragma unroll
      for (int ni = 0; ni < 4; ++ni) {
        const _Float16 hv = (_Float16)(acc[mi][ni][r] + bv[ni]);
        Cws[(size_t)(rowb + mi * 16 + r) * NOUT + colb + ni * 16] =
            __builtin_bit_cast(unsigned short, hv);
      }
    }
  }

  // --- fused vend: each wave's 32 rows = ONE chunk (R13-verified) ---
  {
    float rr[4];
#pragma unroll
    for (int ni = 0; ni < 4; ++ni) {
      const float d  = decay[colb + ni * 16];
      const float bb = bv[ni];
      const float omd = 1.0f - d;
      const float dd = d * d, d4 = dd * dd, d8 = d4 * d4;
      const float d16 = d8 * d8, d12 = d8 * d4;
      const float dpg = (g == 0) ? d12 : (g == 1) ? d8 : (g == 2) ? d4 : 1.0f;
      float s[2];
#pragma unroll
      for (int mi = 0; mi < 2; ++mi) {
        float v = acc[mi][ni][0] + bb;
        v = v * d + (acc[mi][ni][1] + bb);
        v = v * d + (acc[mi][ni][2] + bb);
        v = v * d + (acc[mi][ni][3] + bb);
        s[mi] = omd * v;
      }
      float u = dpg * (s[0] * d16 + s[1]);
      u += __shfl_xor(u, 16); u += __shfl_xor(u, 32);
      rr[ni] = u;
    }
    const int b     = m0 >> 11;
    const int chunk = ((m0 & (TT - 1)) >> 5) + (wm >> 5);
    const float val = (g == 0) ? rr[0] : (g == 1) ? rr[1] : (g == 2) ? rr[2] : rr[3];
    const int col   = n0 + wn + frow + g * 16;
    vend[((size_t)b * NCHUNK + chunk) * NOUT + col] = val;
  }
}

// ---------------------------------------------------------------------------
// Fallback f32 GEMM (verified R1) — only if workspace is too small.
// ---------------------------------------------------------------------------
__global__ __launch_bounds__(256) void gemm_f32_64x64(
    const float* __restrict__ X, const float* __restrict__ W,
    const float* __restrict__ bias, float* __restrict__ C) {
  __shared__ float As[16][65];
  __shared__ float Bs[16][65];
  const int m0  = blockIdx.y * 64;
  const int n0  = blockIdx.x * 64;
  const int tid = threadIdx.x;
  const int tx  = tid & 15;
  const int ty  = tid >> 4;
  const int lr  = tid >> 2;
  const int lk  = (tid & 3) << 2;
  float acc[4][4] = {};
  const float* xa = X + (size_t)(m0 + lr) * KIN + lk;
  const float* wb = W + (size_t)(n0 + lr) * KIN + lk;
  for (int k0 = 0; k0 < KIN; k0 += 16) {
    float4 av = *reinterpret_cast<const float4*>(xa + k0);
    float4 bv = *reinterpret_cast<const float4*>(wb + k0);
    As[lk + 0][lr] = av.x; As[lk + 1][lr] = av.y;
    As[lk + 2][lr] = av.z; As[lk + 3][lr] = av.w;
    Bs[lk + 0][lr] = bv.x; Bs[lk + 1][lr] = bv.y;
    Bs[lk + 2][lr] = bv.z; Bs[lk + 3][lr] = bv.w;
    __syncthreads();
#pragma unroll
    for (int k = 0; k < 16; ++k) {
      float a[4], b[4];
#pragma unroll
      for (int i = 0; i < 4; ++i) a[i] = As[k][ty * 4 + i];
#pragma unroll
      for (int j = 0; j < 4; ++j) b[j] = Bs[k][tx * 4 + j];
#pragma unroll
      for (int i = 0; i < 4; ++i)
#pragma unroll
        for (int j = 0; j < 4; ++j) acc[i][j] += a[i] * b[j];
    }
    __syncthreads();
  }
  const int n = n0 + tx * 4;
  float4 bv = *reinterpret_cast<const float4*>(&bias[n]);
#pragma unroll
  for (int i = 0; i < 4; ++i) {
    const int m = m0 + ty * 4 + i;
    float4 r;
    r.x = acc[i][0] + bv.x; r.y = acc[i][1] + bv.y;
    r.z = acc[i][2] + bv.z; r.w = acc[i][3] + bv.w;
    *reinterpret_cast<float4*>(&C[(size_t)m * NOUT + n]) = r;
  }
}

// ---------------------------------------------------------------------------
// Fixup with integrated chunk-carry compose (verified R11-R13): block (b,c)
// composes vinit from vend, scans its chunk from f16 Cws, writes out+states.
// ---------------------------------------------------------------------------
__global__ __launch_bounds__(512) void scan_fixup2(
    const unsigned short* __restrict__ Cws, const float* __restrict__ vend,
    const float* __restrict__ decay, float* __restrict__ out,
    float* __restrict__ states) {
  const int b = blockIdx.x / NCHUNK;
  const int c = blockIdx.x % NCHUNK;
  const int o = threadIdx.x;
  const float d   = decay[o];
  const float omd = 1.0f - d;
  const float dd = d * d, d4 = dd * dd, d8 = d4 * d4, d16 = d8 * d8;
  const float dL = d16 * d16;   // d^CHUNK

  float v = 0.0f;
  const float* vp = vend + (size_t)b * NCHUNK * NOUT + o;
  for (int cc = 0; cc < c; ++cc) v = dL * v + vp[(size_t)cc * NOUT];

  size_t obase = ((size_t)b * TT + (size_t)c * CHUNK) * NOUT + o;
  size_t sbase = ((size_t)b * (TT + 1) + (size_t)c * CHUNK + 1) * NOUT + o;
#pragma unroll 4
  for (int k = 0; k < CHUNK; ++k) {
    const unsigned short hu = Cws[obase + (size_t)k * NOUT];
    const float cur = (float)__builtin_bit_cast(_Float16, hu);
    v = d * v + omd * cur;
    out[obase + (size_t)k * NOUT]    = v;
    states[sbase + (size_t)k * NOUT] = v;
  }
  if (c == 0) states[((size_t)b * (TT + 1)) * NOUT + o] = 0.0f;
}

__global__ __launch_bounds__(512) void scan_seq(
    float* __restrict__ C, float* __restrict__ states,
    const float* __restrict__ decay) {
  const int b = blockIdx.x;
  const int o = threadIdx.x;
  const float d   = decay[o];
  const float omd = 1.0f - d;
  float v = 0.0f;
  states[((size_t)b * (TT + 1)) * NOUT + o] = 0.0f;
  for (int t = 0; t < TT; ++t) {
    const size_t oi = ((size_t)b * TT + t) * NOUT + o;
    float x = C[oi];
    v = d * v + omd * x;
    C[oi] = v;
    states[((size_t)b * (TT + 1) + t + 1) * NOUT + o] = v;
  }
}

extern "C" void kernel_launch(void* const* d_in, const int* in_sizes, int n_in,
                              void* d_out, int out_size, void* d_ws, size_t ws_size,
                              hipStream_t stream) {
  const float* x     = (const float*)d_in[0];  // [B,T,IN]
  const float* w     = (const float*)d_in[1];  // [OUT,IN]
  const float* bias  = (const float*)d_in[2];  // [OUT]
  const float* decay = (const float*)d_in[3];  // [OUT]

  float* out    = (float*)d_out;                 // [B,T,OUT]
  float* states = out + (size_t)BB * TT * NOUT;  // [1,B,T+1,OUT]

  const size_t szWb = (size_t)NOUT * KIN * sizeof(_Float16);        // 1 MB
  const size_t szCb = (size_t)BB * TT * NOUT * sizeof(_Float16);    // 16.8 MB
  const size_t scan_elems = (size_t)BB * NCHUNK * NOUT;
  const size_t need = szWb + szCb + scan_elems * sizeof(float);     // ~20 MB

  if (ws_size >= need) {
    unsigned char*  Wt   = (unsigned char*)d_ws;
    unsigned short* Cws  = (unsigned short*)(Wt + szWb);
    float*          vend = (float*)(Cws + (size_t)BB * TT * NOUT);

    conv_tiled_f16<<<256, 256, 0, stream>>>(w, Wt, NOUT * (KIN / 8));
    gemm_f16<<<dim3((BB * TT) / BM, NOUT / BN), 256, 0, stream>>>(
        x, Wt, bias, decay, Cws, vend);
    scan_fixup2<<<BB * NCHUNK, NOUT, 0, stream>>>(Cws, vend, decay, out, states);
  } else {
    gemm_f32_64x64<<<dim3(NOUT / 64, (BB * TT) / 64), 256, 0, stream>>>(x, w, bias, out);
    scan_seq<<<BB, NOUT, 0, stream>>>(out, states, decay);
  }
}

// Round 16
// 61.943 us; speedup vs baseline: 1.9494x; 1.0785x over previous
//
#include <hip/hip_runtime.h>
#include <hip/hip_bf16.h>
#include <cstddef>
#include <cstdint>

#define BB    8
#define TT    2048
#define KIN   1024
#define NOUT  512
#define CHUNK 32
#define NCHUNK (TT / CHUNK)   // 64

#define BM 128
#define BN 128
#define BK 32
#define NKSTEP (KIN / BK)     // 32
#define NPAGE  (KIN / 32)     // 32 8KB pages per 128-row strip (W only)
#define TILEB 8192
#define BUFB  24576           // per LDS buffer: A f32 16KB | B f16 8KB

typedef __attribute__((ext_vector_type(4))) float          f32x4;
typedef __attribute__((ext_vector_type(4))) unsigned int   u32x4;
typedef _Float16 f16x8 __attribute__((ext_vector_type(8)));

// ---------------------------------------------------------------------------
// W f32 -> f16 tiled+preswizzled pages (verified R10-R15).  1 MB, ~3 us.
// ---------------------------------------------------------------------------
__global__ __launch_bounds__(256) void conv_tiled_f16(
    const float* __restrict__ src, unsigned char* __restrict__ dst, int total) {
  int idx = blockIdx.x * blockDim.x + threadIdx.x;
  const int stride = gridDim.x * blockDim.x;
  for (; idx < total; idx += stride) {
    const int r  = idx >> 7;
    const int s8 = idx & 127;
    const float* p = src + (size_t)r * KIN + s8 * 8;
    float4 a = *reinterpret_cast<const float4*>(p);
    float4 b = *reinterpret_cast<const float4*>(p + 4);
    f16x8 h;
    h[0] = (_Float16)a.x; h[1] = (_Float16)a.y;
    h[2] = (_Float16)a.z; h[3] = (_Float16)a.w;
    h[4] = (_Float16)b.x; h[5] = (_Float16)b.y;
    h[6] = (_Float16)b.z; h[7] = (_Float16)b.w;
    const int row  = r & 127;
    const int page = (r >> 7) * NPAGE + (s8 >> 2);
    const int slot = (s8 & 3) ^ ((row >> 1) & 3);
    *reinterpret_cast<f16x8*>(dst + (size_t)page * TILEB + row * 64 + slot * 16) = h;
  }
}

#define G2L(gp, sp)                                                        \
  __builtin_amdgcn_global_load_lds(                                       \
      (const __attribute__((address_space(1))) void*)(gp),                \
      (__attribute__((address_space(3))) void*)(sp), 16, 0, 0)

// ---------------------------------------------------------------------------
// fp16 MFMA GEMM — R12's verified core + T3-minimum pipeline:
//   DOUBLE-buffered 2x24KB LDS; each iter ISSUES stage(t+1) into buf^1
//   BEFORE compute(t) from buf; ONE plain __syncthreads() per iter at end.
//   Its implicit vmcnt(0) now waits for loads that flew during the whole
//   compute phase instead of draining immediately (the R5-R15 serial-drain
//   flaw).  Race-free: staged buffer was freed at the previous barrier.
//   BK=32: 32 K-steps, 6 G2L/step (A f32 4, B f16 page 2), 16 MFMA/wave-step.
//   A: direct f32 X, LDS[row][slot]=X[row][slot^(row&7)] (R12-verified math,
//   kk=0 half).  B: pre-swizzled f16 pages (R10-verified).
//   C stored f16 to ws + fused vend epilogue (R11/R12-verified).
//   grid (128 m, 4 n): 128%8==0 -> an m-strip's n-blocks share an XCD.
// ---------------------------------------------------------------------------
__global__ __launch_bounds__(256, 2) void gemm_f16(
    const float* __restrict__ X, const unsigned char* __restrict__ Wt,
    const float* __restrict__ bias, const float* __restrict__ decay,
    unsigned short* __restrict__ Cws, float* __restrict__ vend) {
  __shared__ __align__(16) unsigned char smem[2 * BUFB];  // 48KB

  const int tid  = threadIdx.x;
  const int wave = tid >> 6;
  const int lane = tid & 63;
  const int m0 = blockIdx.x * BM;
  const int n0 = blockIdx.y * BN;
  const int wm = (wave >> 1) * 64;
  const int wn = (wave & 1) * 64;
  const int frow = lane & 15;
  const int g    = lane >> 4;

  // --- A staging map (R12-verified, BK=32 variant): issue q covers rows
  //     q*32..q*32+31; lane handles row (tid>>3), slot (tid&7) of 8;
  //     source slot pre-swizzled so LDS[row][slot] = X[row][slot^(row&7)].
  const int arow  = tid >> 3;          // 0..31
  const int aslot = tid & 7;
  const float* gA = X + (size_t)(m0 + arow) * KIN + ((aslot ^ (arow & 7)) << 2);
  const int ldsw = wave * 1024;

  const unsigned char* srcB = Wt + (size_t)(n0 >> 7) * NPAGE * TILEB + tid * 16;

  const int arswz = frow & 7;
  const int swzr  = (g ^ ((frow >> 1) & 3)) << 4;

  f32x4 acc[4][4] = {};

  auto stage = [&](unsigned char* buf, int t) {
    const int k0 = t * BK;
#pragma unroll
    for (int q = 0; q < 4; ++q)                      // A: 4 x 4KB (32 rows)
      G2L(gA + (size_t)(q * 32) * KIN + k0, buf + q * 4096 + ldsw);
    const size_t boff = (size_t)t * TILEB;           // B: one 8KB page
    G2L(srcB + boff,        buf + 16384 + ldsw);
    G2L(srcB + boff + 4096, buf + 16384 + 4096 + ldsw);
  };

  // prologue: buffer 0 staged and drained
  stage(smem, 0);
  __syncthreads();

  for (int t = 0; t < NKSTEP; ++t) {
    unsigned char* cur = smem + (t & 1) * BUFB;
    unsigned char* nxt = smem + ((t + 1) & 1) * BUFB;

    // 1) issue next tile FIRST (flies under this iter's compute)
    if (t + 1 < NKSTEP) stage(nxt, t + 1);

    // 2) compute(t): A f32 -> pkrtz f16 fragments; B f16 fragments; 16 MFMA
    f16x8 af[4];
#pragma unroll
    for (int mi = 0; mi < 4; ++mi) {
      const int row = wm + mi * 16 + frow;
      const unsigned char* ap = cur + row * 128;
      const int s0 = g * 2;
      f32x4 q0 = *reinterpret_cast<const f32x4*>(ap + ((s0)     ^ arswz) * 16);
      f32x4 q1 = *reinterpret_cast<const f32x4*>(ap + ((s0 + 1) ^ arswz) * 16);
      u32x4 hv;
      hv[0] = __builtin_bit_cast(unsigned int, __builtin_amdgcn_cvt_pkrtz(q0[0], q0[1]));
      hv[1] = __builtin_bit_cast(unsigned int, __builtin_amdgcn_cvt_pkrtz(q0[2], q0[3]));
      hv[2] = __builtin_bit_cast(unsigned int, __builtin_amdgcn_cvt_pkrtz(q1[0], q1[1]));
      hv[3] = __builtin_bit_cast(unsigned int, __builtin_amdgcn_cvt_pkrtz(q1[2], q1[3]));
      af[mi] = __builtin_bit_cast(f16x8, hv);
    }
#pragma unroll
    for (int ni = 0; ni < 4; ++ni) {
      f16x8 bf = *reinterpret_cast<const f16x8*>(
          cur + 16384 + (wn + ni * 16 + frow) * 64 + swzr);
#pragma unroll
      for (int mi = 0; mi < 4; ++mi)
        acc[mi][ni] = __builtin_amdgcn_mfma_f32_16x16x32_f16(af[mi], bf, acc[mi][ni], 0, 0, 0);
    }

    // 3) one barrier: drains stage(t+1) (hidden under compute) + LDS reads
    __syncthreads();
  }

  // --- epilogue: bias + f16 C store to workspace (verified R11/R12) ---
  const int colb = n0 + wn + frow;
  const int rowb = m0 + wm + (g << 2);
  float bv[4];
#pragma unroll
  for (int ni = 0; ni < 4; ++ni) bv[ni] = bias[colb + ni * 16];
#pragma unroll
  for (int mi = 0; mi < 4; ++mi) {
#pragma unroll
    for (int r = 0; r < 4; ++r) {
#pragma unroll
      for (int ni = 0; ni < 4; ++ni) {
        const _Float16 hv = (_Float16)(acc[mi][ni][r] + bv[ni]);
        Cws[(size_t)(rowb + mi * 16 + r) * NOUT + colb + ni * 16] =
            __builtin_bit_cast(unsigned short, hv);
      }
    }
  }

  // --- fused vend: Horner + shfl (verified R8/R10/R11/R12) ---
  {
    float rlo[4], rhi[4];
#pragma unroll
    for (int ni = 0; ni < 4; ++ni) {
      const float d  = decay[colb + ni * 16];
      const float bb = bv[ni];
      const float omd = 1.0f - d;
      const float dd = d * d, d4 = dd * dd, d8 = d4 * d4;
      const float d16 = d8 * d8, d12 = d8 * d4;
      const float dpg = (g == 0) ? d12 : (g == 1) ? d8 : (g == 2) ? d4 : 1.0f;
      float s[4];
#pragma unroll
      for (int mi = 0; mi < 4; ++mi) {
        float v = acc[mi][ni][0] + bb;
        v = v * d + (acc[mi][ni][1] + bb);
        v = v * d + (acc[mi][ni][2] + bb);
        v = v * d + (acc[mi][ni][3] + bb);
        s[mi] = omd * v;
      }
      float ulo = dpg * (s[0] * d16 + s[1]);
      float uhi = dpg * (s[2] * d16 + s[3]);
      ulo += __shfl_xor(ulo, 16); ulo += __shfl_xor(ulo, 32);
      uhi += __shfl_xor(uhi, 16); uhi += __shfl_xor(uhi, 32);
      rlo[ni] = ulo; rhi[ni] = uhi;
    }
    const int b   = m0 >> 11;
    const int clo = ((m0 & (TT - 1)) >> 5) + (wm >> 5);
    const int chunk = clo + (g >> 1);
    const int half  = g >> 1;
    const int nia   = g & 1;
    const float v1 = half ? (nia ? rhi[1] : rhi[0]) : (nia ? rlo[1] : rlo[0]);
    const float v2 = half ? (nia ? rhi[3] : rhi[2]) : (nia ? rlo[3] : rlo[2]);
    const int col1 = n0 + wn + frow + nia * 16;
    float* vp = vend + ((size_t)b * NCHUNK + chunk) * NOUT;
    vp[col1]      = v1;
    vp[col1 + 32] = v2;
  }
}

// ---------------------------------------------------------------------------
// Fallback f32 GEMM (verified R1) — only if workspace is too small.
// ---------------------------------------------------------------------------
__global__ __launch_bounds__(256) void gemm_f32_64x64(
    const float* __restrict__ X, const float* __restrict__ W,
    const float* __restrict__ bias, float* __restrict__ C) {
  __shared__ float As[16][65];
  __shared__ float Bs[16][65];
  const int m0  = blockIdx.y * 64;
  const int n0  = blockIdx.x * 64;
  const int tid = threadIdx.x;
  const int tx  = tid & 15;
  const int ty  = tid >> 4;
  const int lr  = tid >> 2;
  const int lk  = (tid & 3) << 2;
  float acc[4][4] = {};
  const float* xa = X + (size_t)(m0 + lr) * KIN + lk;
  const float* wb = W + (size_t)(n0 + lr) * KIN + lk;
  for (int k0 = 0; k0 < KIN; k0 += 16) {
    float4 av = *reinterpret_cast<const float4*>(xa + k0);
    float4 bv = *reinterpret_cast<const float4*>(wb + k0);
    As[lk + 0][lr] = av.x; As[lk + 1][lr] = av.y;
    As[lk + 2][lr] = av.z; As[lk + 3][lr] = av.w;
    Bs[lk + 0][lr] = bv.x; Bs[lk + 1][lr] = bv.y;
    Bs[lk + 2][lr] = bv.z; Bs[lk + 3][lr] = bv.w;
    __syncthreads();
#pragma unroll
    for (int k = 0; k < 16; ++k) {
      float a[4], b[4];
#pragma unroll
      for (int i = 0; i < 4; ++i) a[i] = As[k][ty * 4 + i];
#pragma unroll
      for (int j = 0; j < 4; ++j) b[j] = Bs[k][tx * 4 + j];
#pragma unroll
      for (int i = 0; i < 4; ++i)
#pragma unroll
        for (int j = 0; j < 4; ++j) acc[i][j] += a[i] * b[j];
    }
    __syncthreads();
  }
  const int n = n0 + tx * 4;
  float4 bv = *reinterpret_cast<const float4*>(&bias[n]);
#pragma unroll
  for (int i = 0; i < 4; ++i) {
    const int m = m0 + ty * 4 + i;
    float4 r;
    r.x = acc[i][0] + bv.x; r.y = acc[i][1] + bv.y;
    r.z = acc[i][2] + bv.z; r.w = acc[i][3] + bv.w;
    *reinterpret_cast<float4*>(&C[(size_t)m * NOUT + n]) = r;
  }
}

// ---------------------------------------------------------------------------
// Fixup with integrated chunk-carry compose (verified R11-R15): block (b,c)
// composes vinit from vend, scans its chunk from f16 Cws, writes out+states.
// ---------------------------------------------------------------------------
__global__ __launch_bounds__(512) void scan_fixup2(
    const unsigned short* __restrict__ Cws, const float* __restrict__ vend,
    const float* __restrict__ decay, float* __restrict__ out,
    float* __restrict__ states) {
  const int b = blockIdx.x / NCHUNK;
  const int c = blockIdx.x % NCHUNK;
  const int o = threadIdx.x;
  const float d   = decay[o];
  const float omd = 1.0f - d;
  const float dd = d * d, d4 = dd * dd, d8 = d4 * d4, d16 = d8 * d8;
  const float dL = d16 * d16;   // d^CHUNK

  float v = 0.0f;
  const float* vp = vend + (size_t)b * NCHUNK * NOUT + o;
  for (int cc = 0; cc < c; ++cc) v = dL * v + vp[(size_t)cc * NOUT];

  size_t obase = ((size_t)b * TT + (size_t)c * CHUNK) * NOUT + o;
  size_t sbase = ((size_t)b * (TT + 1) + (size_t)c * CHUNK + 1) * NOUT + o;
#pragma unroll 4
  for (int k = 0; k < CHUNK; ++k) {
    const unsigned short hu = Cws[obase + (size_t)k * NOUT];
    const float cur = (float)__builtin_bit_cast(_Float16, hu);
    v = d * v + omd * cur;
    out[obase + (size_t)k * NOUT]    = v;
    states[sbase + (size_t)k * NOUT] = v;
  }
  if (c == 0) states[((size_t)b * (TT + 1)) * NOUT + o] = 0.0f;
}

__global__ __launch_bounds__(512) void scan_seq(
    float* __restrict__ C, float* __restrict__ states,
    const float* __restrict__ decay) {
  const int b = blockIdx.x;
  const int o = threadIdx.x;
  const float d   = decay[o];
  const float omd = 1.0f - d;
  float v = 0.0f;
  states[((size_t)b * (TT + 1)) * NOUT + o] = 0.0f;
  for (int t = 0; t < TT; ++t) {
    const size_t oi = ((size_t)b * TT + t) * NOUT + o;
    float x = C[oi];
    v = d * v + omd * x;
    C[oi] = v;
    states[((size_t)b * (TT + 1) + t + 1) * NOUT + o] = v;
  }
}

extern "C" void kernel_launch(void* const* d_in, const int* in_sizes, int n_in,
                              void* d_out, int out_size, void* d_ws, size_t ws_size,
                              hipStream_t stream) {
  const float* x     = (const float*)d_in[0];  // [B,T,IN]
  const float* w     = (const float*)d_in[1];  // [OUT,IN]
  const float* bias  = (const float*)d_in[2];  // [OUT]
  const float* decay = (const float*)d_in[3];  // [OUT]

  float* out    = (float*)d_out;                 // [B,T,OUT]
  float* states = out + (size_t)BB * TT * NOUT;  // [1,B,T+1,OUT]

  const size_t szWb = (size_t)NOUT * KIN * sizeof(_Float16);        // 1 MB
  const size_t szCb = (size_t)BB * TT * NOUT * sizeof(_Float16);    // 16.8 MB
  const size_t scan_elems = (size_t)BB * NCHUNK * NOUT;
  const size_t need = szWb + szCb + scan_elems * sizeof(float);     // ~20 MB

  if (ws_size >= need) {
    unsigned char*  Wt   = (unsigned char*)d_ws;
    unsigned short* Cws  = (unsigned short*)(Wt + szWb);
    float*          vend = (float*)(Cws + (size_t)BB * TT * NOUT);

    conv_tiled_f16<<<256, 256, 0, stream>>>(w, Wt, NOUT * (KIN / 8));
    gemm_f16<<<dim3((BB * TT) / BM, NOUT / BN), 256, 0, stream>>>(
        x, Wt, bias, decay, Cws, vend);
    scan_fixup2<<<BB * NCHUNK, NOUT, 0, stream>>>(Cws, vend, decay, out, states);
  } else {
    gemm_f32_64x64<<<dim3(NOUT / 64, (BB * TT) / 64), 256, 0, stream>>>(x, w, bias, out);
    scan_seq<<<BB, NOUT, 0, stream>>>(out, states, decay);
  }
}